// Round 4
// baseline (329.522 us; speedup 1.0000x reference)
//
#include <hip/hip_runtime.h>

typedef short  s16x8 __attribute__((ext_vector_type(8)));   // 8 bf16 bit patterns
typedef float  f32x4 __attribute__((ext_vector_type(4)));
typedef float  f32x2 __attribute__((ext_vector_type(2)));
typedef unsigned int u32;
typedef unsigned int u32x4 __attribute__((ext_vector_type(4)));
typedef unsigned short u16;

#define DEVI static __device__ __forceinline__

constexpr int T_  = 128;
constexpr int F_  = 14;
constexpr int H_  = 64;
constexpr int BPW = 16;   // batch rows per block (one wave)

DEVI u16 f2bf(float f) {                     // RNE, one-time weight convert
  u32 u = __builtin_bit_cast(u32, f);
  u += 0x7fffu + ((u >> 16) & 1u);
  return (u16)(u >> 16);
}
DEVI u16 f2bfF(float f) {                    // round-half-up, in-loop (add+shift)
  u32 u = __builtin_bit_cast(u32, f);
  return (u16)((u + 0x8000u) >> 16);
}
DEVI u32 pkbf(float a, float b) {            // pack 2 bf16 into one dword
  u32 ua = __builtin_bit_cast(u32, a) + 0x8000u;
  u32 ub = __builtin_bit_cast(u32, b) + 0x8000u;
  return (ua >> 16) | (ub & 0xffff0000u);
}
// B-frag kt from tanh'd acc tiles: elements 0-3 = tile kt, 4-7 = tile kt+2
DEVI s16x8 packfrag(const f32x4& a, const f32x4& b) {
  u32x4 p;
  p[0] = pkbf(a[0], a[1]); p[1] = pkbf(a[2], a[3]);
  p[2] = pkbf(b[0], b[1]); p[3] = pkbf(b[2], b[3]);
  return __builtin_bit_cast(s16x8, p);
}
DEVI float tanhfast(float x) {
  float e = exp2f(x * -2.8853900817779268f);
  float r = __builtin_amdgcn_rcpf(1.0f + e);
  return __builtin_fmaf(2.0f, r, -1.0f);
}
DEVI f32x4 tanh4(const f32x4& v) {
  f32x4 r;
  r[0] = tanhfast(v[0]); r[1] = tanhfast(v[1]);
  r[2] = tanhfast(v[2]); r[3] = tanhfast(v[3]);
  return r;
}
DEVI f32x4 MFMA(s16x8 a, s16x8 b, f32x4 c) {
  return __builtin_amdgcn_mfma_f32_16x16x32_bf16(a, b, c, 0, 0, 0);
}
// 8 contiguous fp32 (16B-aligned) -> bf16 A-frag
DEVI s16x8 ldrow8(const float* p) {
  const f32x4 a = ((const f32x4*)p)[0];
  const f32x4 b = ((const f32x4*)p)[1];
  s16x8 r;
  r[0] = (short)f2bf(a[0]); r[1] = (short)f2bf(a[1]);
  r[2] = (short)f2bf(a[2]); r[3] = (short)f2bf(a[3]);
  r[4] = (short)f2bf(b[0]); r[5] = (short)f2bf(b[1]);
  r[6] = (short)f2bf(b[2]); r[7] = (short)f2bf(b[3]);
  return r;
}

// One wave per block owns 16 batch rows and the FULL hidden dim.
// Row permutation L(n,rho) = 32*(n&1) + 8*(rho>>2) + 4*(n>>1) + (rho&3) makes the
// MFMA C/D layout coincide with the next MFMA's B layout lane-for-lane:
//   F[kt] = packfrag(tanh(acc[kt]), tanh(acc[kt+2]))  — pure register repack,
// so the T-loop has NO barriers and NO LDS dependencies between lanes.
// Cold weights (Wih1/Wih2 frags + layer1/2 biases) are parked in LDS and
// re-read each step (same-wave, no sync) to keep VGPRs under the spill line.
__global__ __launch_bounds__(64, 1) void rnn_1w(
    const float* __restrict__ x,
    const float* __restrict__ Wih0, const float* __restrict__ Whh0,
    const float* __restrict__ bih0, const float* __restrict__ bhh0,
    const float* __restrict__ Wih1, const float* __restrict__ Whh1,
    const float* __restrict__ bih1, const float* __restrict__ bhh1,
    const float* __restrict__ Wih2, const float* __restrict__ Whh2,
    const float* __restrict__ bih2, const float* __restrict__ bhh2,
    const float* __restrict__ fc1w, const float* __restrict__ fc1b,
    const float* __restrict__ fc2w, const float* __restrict__ fc2b,
    float* __restrict__ out)
{
  __shared__ __align__(16) u32x4 Wp[16][64];   // 0-7: A1i[n][kt], 8-15: A2i[n][kt]
  __shared__ __align__(16) f32x4 Bp[8][64];    // 0-3: bc1[n], 4-7: bc2[n]
  __shared__ __align__(16) float h2l[BPW][68]; // fc-head unpermute scratch

  const int lane = threadIdx.x & 63;
  const int g    = lane >> 4;
  const int m    = lane & 15;
  const int b0   = blockIdx.x * BPW;

  // ---- resident weights: A0x, A0h, A1h, A2h (28 frags = 112 VGPRs) + bc0 ----
  s16x8 A0x[4], A0h[4][2], A1h[4][2], A2h[4][2];
  f32x4 bc0[4];
  #pragma unroll
  for (int n = 0; n < 4; n++) {
    const int Lr = 32 * (n & 1) + 8 * (m >> 2) + 4 * (n >> 1) + (m & 3);
    { // layer0 x-part: k = 8g+j, valid k < 14, zero pad to 32
      s16x8 r;
      #pragma unroll
      for (int j2 = 0; j2 < 8; j2++) {
        const int kk = 8 * g + j2;
        r[j2] = (kk < F_) ? (short)f2bf(Wih0[Lr * F_ + kk]) : (short)0;
      }
      A0x[n] = r;
    }
    #pragma unroll
    for (int kt = 0; kt < 2; kt++) {
      const int ko = 32 * kt + 8 * g;
      A0h[n][kt] = ldrow8(Whh0 + Lr * H_ + ko);
      A1h[n][kt] = ldrow8(Whh1 + Lr * H_ + ko);
      A2h[n][kt] = ldrow8(Whh2 + Lr * H_ + ko);
      // park input-side weights of layers 1/2 in LDS (per-lane frags)
      Wp[2 * n + kt][lane]     = __builtin_bit_cast(u32x4, ldrow8(Wih1 + Lr * H_ + ko));
      Wp[8 + 2 * n + kt][lane] = __builtin_bit_cast(u32x4, ldrow8(Wih2 + Lr * H_ + ko));
    }
    const int Lb = 32 * (n & 1) + 8 * g + 4 * (n >> 1);  // acc reg r <-> row Lb+r
    bc0[n] = *(const f32x4*)(bih0 + Lb) + *(const f32x4*)(bhh0 + Lb);
    Bp[n][lane]     = *(const f32x4*)(bih1 + Lb) + *(const f32x4*)(bhh1 + Lb);
    Bp[4 + n][lane] = *(const f32x4*)(bih2 + Lb) + *(const f32x4*)(bhh2 + Lb);
  }

  auto ldsW = [&](int idx) -> s16x8 {
    return __builtin_bit_cast(s16x8, Wp[idx][lane]);   // ds_read_b128, same-wave
  };

  // ---- h-state frags, zero init ----
  s16x8 F0[2], F1[2], F2[2];
  {
    s16x8 z;
    #pragma unroll
    for (int i = 0; i < 8; i++) z[i] = 0;
    F0[0] = z; F0[1] = z; F1[0] = z; F1[1] = z; F2[0] = z; F2[1] = z;
  }

  // ---- x pipeline: raw fp32 regs, distance-2 prefetch, convert late ----
  const float* xrow = x + (size_t)(b0 + m) * T_ * F_;
  auto ldraw = [&](int t, f32x4& ra, f32x4& rb) {   // 8B-aligned float2 loads
    const float* p = xrow + t * F_;
    if (g == 0) {
      f32x2 p0 = *(const f32x2*)(p),     p1 = *(const f32x2*)(p + 2);
      f32x2 p2 = *(const f32x2*)(p + 4), p3 = *(const f32x2*)(p + 6);
      ra[0] = p0[0]; ra[1] = p0[1]; ra[2] = p1[0]; ra[3] = p1[1];
      rb[0] = p2[0]; rb[1] = p2[1]; rb[2] = p3[0]; rb[3] = p3[1];
    } else if (g == 1) {
      f32x2 p4 = *(const f32x2*)(p + 8), p5 = *(const f32x2*)(p + 10);
      f32x2 p6 = *(const f32x2*)(p + 12);
      ra[0] = p4[0]; ra[1] = p4[1]; ra[2] = p5[0]; ra[3] = p5[1];
      rb[0] = p6[0]; rb[1] = p6[1]; rb[2] = 0.f;   rb[3] = 0.f;
    } else {
      ra[0] = 0.f; ra[1] = 0.f; ra[2] = 0.f; ra[3] = 0.f;
      rb[0] = 0.f; rb[1] = 0.f; rb[2] = 0.f; rb[3] = 0.f;
    }
  };
  auto cvtraw = [&](const f32x4& ra, const f32x4& rb) -> s16x8 {
    s16x8 r;
    r[0] = (short)f2bfF(ra[0]); r[1] = (short)f2bfF(ra[1]);
    r[2] = (short)f2bfF(ra[2]); r[3] = (short)f2bfF(ra[3]);
    r[4] = (short)f2bfF(rb[0]); r[5] = (short)f2bfF(rb[1]);
    r[6] = (short)f2bfF(rb[2]); r[7] = (short)f2bfF(rb[3]);
    return r;
  };

  f32x4 rA0, rA1, rB0, rB1;
  ldraw(0, rA0, rA1);
  s16x8 bx = cvtraw(rA0, rA1);    // frag for t=0
  ldraw(1, rA0, rA1);             // raw for t=1

  f32x4 h2v[4];

  #pragma unroll 1
  for (int t = 0; t < T_; t++) {
    ldraw(t + 2 < T_ ? t + 2 : T_ - 1, rB0, rB1);   // in-flight during this step

    f32x4 a0[4], a1[4], a2[4], hv[4];

    // phase A: layer0 full + layer1 hh-part (indep of this step's activations)
    #pragma unroll
    for (int n = 0; n < 4; n++) {
      f32x4 a = bc0[n];
      a = MFMA(A0x[n], bx, a);
      a = MFMA(A0h[n][0], F0[0], a);
      a = MFMA(A0h[n][1], F0[1], a);
      a0[n] = a;
    }
    #pragma unroll
    for (int n = 0; n < 4; n++) {
      f32x4 a = Bp[n][lane];
      a = MFMA(A1h[n][0], F1[0], a);
      a = MFMA(A1h[n][1], F1[1], a);
      a1[n] = a;
    }

    // activation 0 -> F0 (register repack), then layer1 input-part from LDS
    #pragma unroll
    for (int n = 0; n < 4; n++) hv[n] = tanh4(a0[n]);
    F0[0] = packfrag(hv[0], hv[2]);
    F0[1] = packfrag(hv[1], hv[3]);
    #pragma unroll
    for (int n = 0; n < 4; n++) {
      a1[n] = MFMA(ldsW(2 * n),     F0[0], a1[n]);
      a1[n] = MFMA(ldsW(2 * n + 1), F0[1], a1[n]);
    }

    // layer2 hh-part (uses old F2; placed here to cap acc liveness at 2 sets)
    #pragma unroll
    for (int n = 0; n < 4; n++) {
      f32x4 a = Bp[4 + n][lane];
      a = MFMA(A2h[n][0], F2[0], a);
      a = MFMA(A2h[n][1], F2[1], a);
      a2[n] = a;
    }

    // activation 1 -> F1, then layer2 input-part from LDS
    #pragma unroll
    for (int n = 0; n < 4; n++) hv[n] = tanh4(a1[n]);
    F1[0] = packfrag(hv[0], hv[2]);
    F1[1] = packfrag(hv[1], hv[3]);
    #pragma unroll
    for (int n = 0; n < 4; n++) {
      a2[n] = MFMA(ldsW(8 + 2 * n),     F1[0], a2[n]);
      a2[n] = MFMA(ldsW(8 + 2 * n + 1), F1[1], a2[n]);
    }

    // activation 2 -> F2 (fp32 copy kept for head)
    #pragma unroll
    for (int n = 0; n < 4; n++) h2v[n] = tanh4(a2[n]);
    F2[0] = packfrag(h2v[0], h2v[2]);
    F2[1] = packfrag(h2v[1], h2v[3]);

    // rotate x pipeline: convert raw(t+1) loaded last step; keep t+2 in flight
    bx  = cvtraw(rA0, rA1);
    rA0 = rB0; rA1 = rB1;
  }

  // ---- FC head: un-permute h2 through LDS, dot products, reduce ----
  #pragma unroll
  for (int n = 0; n < 4; n++) {
    const int Lb = 32 * (n & 1) + 8 * g + 4 * (n >> 1);
    *(f32x4*)&h2l[m][Lb] = h2v[n];
  }
  __syncthreads();   // single wave: trivial; orders LDS for cross-lane read

  float hr[64];
  #pragma unroll
  for (int q = 0; q < 16; q++) {
    f32x4 v = *(const f32x4*)&h2l[m][4 * q];
    hr[4 * q + 0] = v[0]; hr[4 * q + 1] = v[1];
    hr[4 * q + 2] = v[2]; hr[4 * q + 3] = v[3];
  }
  float acc2 = 0.f;
  #pragma unroll
  for (int jj = 0; jj < 8; jj++) {
    const int jf = 8 * g + jj;
    float s = fc1b[jf];
    const f32x4* wp = (const f32x4*)(fc1w + jf * H_);
    #pragma unroll
    for (int kq = 0; kq < 16; kq++) {
      f32x4 wv = wp[kq];
      s += hr[4 * kq + 0] * wv[0] + hr[4 * kq + 1] * wv[1]
         + hr[4 * kq + 2] * wv[2] + hr[4 * kq + 3] * wv[3];
    }
    s = fmaxf(s, 0.f);
    acc2 += s * fc2w[jf];
  }
  acc2 += __shfl_xor(acc2, 16, 64);
  acc2 += __shfl_xor(acc2, 32, 64);
  if (lane < 16) out[b0 + m] = acc2 + fc2b[0];
}

extern "C" void kernel_launch(void* const* d_in, const int* in_sizes, int n_in,
                              void* d_out, int out_size, void* d_ws, size_t ws_size,
                              hipStream_t stream) {
  const float* x    = (const float*)d_in[0];
  const float* Wih0 = (const float*)d_in[1];
  const float* Whh0 = (const float*)d_in[2];
  const float* bih0 = (const float*)d_in[3];
  const float* bhh0 = (const float*)d_in[4];
  const float* Wih1 = (const float*)d_in[5];
  const float* Whh1 = (const float*)d_in[6];
  const float* bih1 = (const float*)d_in[7];
  const float* bhh1 = (const float*)d_in[8];
  const float* Wih2 = (const float*)d_in[9];
  const float* Whh2 = (const float*)d_in[10];
  const float* bih2 = (const float*)d_in[11];
  const float* bhh2 = (const float*)d_in[12];
  const float* fc1w = (const float*)d_in[13];
  const float* fc1b = (const float*)d_in[14];
  const float* fc2w = (const float*)d_in[15];
  const float* fc2b = (const float*)d_in[16];

  rnn_1w<<<dim3(4096 / BPW), dim3(64), 0, stream>>>(
      x, Wih0, Whh0, bih0, bhh0, Wih1, Whh1, bih1, bhh1,
      Wih2, Whh2, bih2, bhh2, fc1w, fc1b, fc2w, fc2b, (float*)d_out);
}

// Round 5
// 234.593 us; speedup vs baseline: 1.4047x; 1.4047x over previous
//
#include <hip/hip_runtime.h>

typedef short  s16x8 __attribute__((ext_vector_type(8)));   // 8 bf16 bit patterns
typedef float  f32x4 __attribute__((ext_vector_type(4)));
typedef unsigned int u32;
typedef unsigned int u32x4 __attribute__((ext_vector_type(4)));
typedef unsigned short u16;

#define DEVI static __device__ __forceinline__

constexpr int T_  = 128;
constexpr int F_  = 14;
constexpr int H_  = 64;
constexpr int BPB = 16;   // batch rows per block

DEVI u16 f2bf(float f) {                     // RNE, one-time weight convert
  u32 u = __builtin_bit_cast(u32, f);
  u += 0x7fffu + ((u >> 16) & 1u);
  return (u16)(u >> 16);
}
DEVI u16 f2bfF(float f) {                    // round-half-up (matches prior rounds' x/h path)
  u32 u = __builtin_bit_cast(u32, f);
  return (u16)((u + 0x8000u) >> 16);
}
DEVI u32 pkbf(float a, float b) {            // pack 2 bf16 into one dword
  u32 ua = __builtin_bit_cast(u32, a) + 0x8000u;
  u32 ub = __builtin_bit_cast(u32, b) + 0x8000u;
  return (ua >> 16) | (ub & 0xffff0000u);
}
// B-frag kt from tanh'd acc tiles: elements 0-3 = tile kt, 4-7 = tile kt+2
DEVI s16x8 packfrag(const f32x4& a, const f32x4& b) {
  u32x4 p;
  p[0] = pkbf(a[0], a[1]); p[1] = pkbf(a[2], a[3]);
  p[2] = pkbf(b[0], b[1]); p[3] = pkbf(b[2], b[3]);
  return __builtin_bit_cast(s16x8, p);
}
DEVI float tanhfast(float x) {
  float e = exp2f(x * -2.8853900817779268f);
  float r = __builtin_amdgcn_rcpf(1.0f + e);
  return __builtin_fmaf(2.0f, r, -1.0f);
}
DEVI f32x4 tanh4(const f32x4& v) {
  f32x4 r;
  r[0] = tanhfast(v[0]); r[1] = tanhfast(v[1]);
  r[2] = tanhfast(v[2]); r[3] = tanhfast(v[3]);
  return r;
}
DEVI f32x4 MFMA(s16x8 a, s16x8 b, f32x4 c) {
  return __builtin_amdgcn_mfma_f32_16x16x32_bf16(a, b, c, 0, 0, 0);
}
// 8 contiguous fp32 (16B-aligned) -> bf16 A-frag
DEVI s16x8 ldrow8(const float* p) {
  const f32x4 a = ((const f32x4*)p)[0];
  const f32x4 b = ((const f32x4*)p)[1];
  s16x8 r;
  r[0] = (short)f2bf(a[0]); r[1] = (short)f2bf(a[1]);
  r[2] = (short)f2bf(a[2]); r[3] = (short)f2bf(a[3]);
  r[4] = (short)f2bf(b[0]); r[5] = (short)f2bf(b[1]);
  r[6] = (short)f2bf(b[2]); r[7] = (short)f2bf(b[3]);
  return r;
}

// 3 waves per block; wave L owns layer L completely (weights+bias+hh-state in regs).
// Software pipeline across time: wave L at epoch e computes step t=e-L.
// Row permutation L(n,rho)=32*(n&1)+8*(rho>>2)+4*(n>>1)+(rho&3) makes the MFMA C/D
// layout equal the next MFMA's B layout lane-for-lane: handoff is a 32B/lane LDS
// write+read, hh-feedback never leaves registers. x is fully staged to LDS (bf16)
// up front so the T-loop has ZERO global memory ops (barrier vmcnt drains are free).
__global__ __launch_bounds__(192, 1) void rnn_pipe(
    const float* __restrict__ x,
    const float* __restrict__ Wih0, const float* __restrict__ Whh0,
    const float* __restrict__ bih0, const float* __restrict__ bhh0,
    const float* __restrict__ Wih1, const float* __restrict__ Whh1,
    const float* __restrict__ bih1, const float* __restrict__ bhh1,
    const float* __restrict__ Wih2, const float* __restrict__ Whh2,
    const float* __restrict__ bih2, const float* __restrict__ bhh2,
    const float* __restrict__ fc1w, const float* __restrict__ fc1b,
    const float* __restrict__ fc2w, const float* __restrict__ fc2b,
    float* __restrict__ out)
{
  __shared__ __align__(16) u16   xl[T_][BPB][F_];   // 57344 B, whole x tile as bf16
  __shared__ __align__(16) u32x4 h0b[2][64];        // 2048 B  [frag][lane]
  __shared__ __align__(16) u32x4 h1b[2][64];        // 2048 B

  const int tid  = threadIdx.x;
  const int w    = tid >> 6;        // wave id = layer id
  const int lane = tid & 63;
  const int g    = lane >> 4;
  const int m    = lane & 15;
  const int b0   = blockIdx.x * BPB;

  // ---- preload x -> LDS as bf16 (batched for memory-level parallelism) ----
  {
    constexpr int NX = BPB * T_ * F_;     // 28672
    u16* xf = &xl[0][0][0];
    #pragma unroll 1
    for (int i0 = tid; i0 < NX; i0 += 192 * 8) {
      float v[8]; int off[8]; bool ok[8];
      #pragma unroll
      for (int u = 0; u < 8; u++) {
        int i = i0 + 192 * u;
        ok[u] = (i < NX);
        if (!ok[u]) i = NX - 1;           // clamp: address always in-bounds
        const int mm = i / (T_ * F_), q = i - mm * (T_ * F_);
        const int tt = q / F_, kk = q - tt * F_;
        off[u] = tt * (BPB * F_) + mm * F_ + kk;
        v[u] = x[(size_t)(b0 + mm) * (T_ * F_) + q];
      }
      #pragma unroll
      for (int u = 0; u < 8; u++) if (ok[u]) xf[off[u]] = f2bfF(v[u]);
    }
  }

  // ---- per-wave (per-layer) weights, all register-resident ----
  s16x8 Ax[4], Ai[4][2], Ah[4][2];
  f32x4 bc[4];
  {
    const float* Wi = Wih1; const float* Wh = Whh0;
    const float* bi = bih0; const float* bh = bhh0;
    if (w == 1)      { Wi = Wih1; Wh = Whh1; bi = bih1; bh = bhh1; }
    else if (w == 2) { Wi = Wih2; Wh = Whh2; bi = bih2; bh = bhh2; }
    #pragma unroll
    for (int n = 0; n < 4; n++) {
      const int Lr = 32 * (n & 1) + 8 * (m >> 2) + 4 * (n >> 1) + (m & 3);
      if (w == 0) {           // layer0 input side: 64x14, zero-pad k to 32
        s16x8 r;
        #pragma unroll
        for (int j2 = 0; j2 < 8; j2++) {
          const int kk = 8 * g + j2;
          r[j2] = (kk < F_) ? (short)f2bf(Wih0[Lr * F_ + kk]) : (short)0;
        }
        Ax[n] = r;
        Ai[n][0] = r; Ai[n][1] = r;       // dead in wave0, keep defined
      } else {
        #pragma unroll
        for (int kt = 0; kt < 2; kt++)
          Ai[n][kt] = ldrow8(Wi + Lr * H_ + 32 * kt + 8 * g);
        Ax[n] = Ai[n][0];                 // dead in waves 1/2
      }
      #pragma unroll
      for (int kt = 0; kt < 2; kt++)
        Ah[n][kt] = ldrow8(Wh + Lr * H_ + 32 * kt + 8 * g);
      const int Lb = 32 * (n & 1) + 8 * g + 4 * (n >> 1);
      bc[n] = *(const f32x4*)(bi + Lb) + *(const f32x4*)(bh + Lb);
    }
  }

  // ---- hh-state frags (per wave's own layer), zero init ----
  s16x8 F[2];
  {
    s16x8 z;
    #pragma unroll
    for (int i = 0; i < 8; i++) z[i] = 0;
    F[0] = z; F[1] = z;
  }
  f32x4 h2v[4];
  #pragma unroll
  for (int n = 0; n < 4; n++) { h2v[n][0] = 0; h2v[n][1] = 0; h2v[n][2] = 0; h2v[n][3] = 0; }

  __syncthreads();   // xl visible to wave0

  // ---- pipelined T-loop: epoch e, wave w computes step t = e - w ----
  #pragma unroll 1
  for (int e = 0; e < T_ + 2; e++) {
    const int t = e - w;
    const bool act = (t >= 0) & (t < T_);

    // phase R: read this epoch's inputs (produced before the last END barrier)
    s16x8 bx, binf0, binf1;
    if (w == 0) {
      u32 x0 = 0, x1 = 0, x2 = 0, x3 = 0;
      if (act) {
        const u32* bp = (const u32*)&xl[t][m][0];   // 4B-aligned (28B row stride)
        if (g == 0)      { x0 = bp[0]; x1 = bp[1]; x2 = bp[2]; x3 = bp[3]; }
        else if (g == 1) { x0 = bp[4]; x1 = bp[5]; x2 = bp[6]; }
      }
      u32x4 xv; xv[0] = x0; xv[1] = x1; xv[2] = x2; xv[3] = x3;
      bx = __builtin_bit_cast(s16x8, xv);
      binf0 = bx; binf1 = bx;             // dead in wave0
    } else if (w == 1) {
      binf0 = __builtin_bit_cast(s16x8, h0b[0][lane]);
      binf1 = __builtin_bit_cast(s16x8, h0b[1][lane]);
      bx = binf0;
    } else {
      binf0 = __builtin_bit_cast(s16x8, h1b[0][lane]);
      binf1 = __builtin_bit_cast(s16x8, h1b[1][lane]);
      bx = binf0;
    }
    __syncthreads();   // MID: all reads of h0b/h1b complete before overwrites

    // phase W: compute step t and publish handoff
    if (act) {
      f32x4 a[4];
      #pragma unroll
      for (int n = 0; n < 4; n++) a[n] = bc[n];
      if (w == 0) {
        #pragma unroll
        for (int n = 0; n < 4; n++) a[n] = MFMA(Ax[n], bx, a[n]);
      } else {
        #pragma unroll
        for (int n = 0; n < 4; n++) {
          a[n] = MFMA(Ai[n][0], binf0, a[n]);
          a[n] = MFMA(Ai[n][1], binf1, a[n]);
        }
      }
      #pragma unroll
      for (int n = 0; n < 4; n++) {
        a[n] = MFMA(Ah[n][0], F[0], a[n]);
        a[n] = MFMA(Ah[n][1], F[1], a[n]);
      }
      f32x4 hv[4];
      #pragma unroll
      for (int n = 0; n < 4; n++) hv[n] = tanh4(a[n]);
      F[0] = packfrag(hv[0], hv[2]);
      F[1] = packfrag(hv[1], hv[3]);
      if (w == 0) {
        h0b[0][lane] = __builtin_bit_cast(u32x4, F[0]);
        h0b[1][lane] = __builtin_bit_cast(u32x4, F[1]);
      } else if (w == 1) {
        h1b[0][lane] = __builtin_bit_cast(u32x4, F[0]);
        h1b[1][lane] = __builtin_bit_cast(u32x4, F[1]);
      } else if (t == T_ - 1) {
        #pragma unroll
        for (int n = 0; n < 4; n++) h2v[n] = hv[n];   // keep fp32 h2 for head
      }
    }
    __syncthreads();   // END: handoff visible to next epoch's readers
  }

  // ---- FC head: wave2 un-permutes fp32 h2 into (dead) xl region, wave0 computes ----
  float (*h2l)[68] = (float (*)[68])(&xl[0][0][0]);
  if (w == 2) {
    #pragma unroll
    for (int n = 0; n < 4; n++) {
      const int Lb = 32 * (n & 1) + 8 * g + 4 * (n >> 1);
      *(f32x4*)&h2l[m][Lb] = h2v[n];
    }
  }
  __syncthreads();

  if (w == 0) {
    float hr[64];
    #pragma unroll
    for (int q = 0; q < 16; q++) {
      f32x4 v = *(const f32x4*)&h2l[m][4 * q];
      hr[4 * q + 0] = v[0]; hr[4 * q + 1] = v[1];
      hr[4 * q + 2] = v[2]; hr[4 * q + 3] = v[3];
    }
    float acc2 = 0.f;
    #pragma unroll
    for (int jj = 0; jj < 8; jj++) {
      const int jf = 8 * g + jj;
      float s = fc1b[jf];
      const f32x4* wp = (const f32x4*)(fc1w + jf * H_);
      #pragma unroll
      for (int kq = 0; kq < 16; kq++) {
        f32x4 wv = wp[kq];
        s += hr[4 * kq + 0] * wv[0] + hr[4 * kq + 1] * wv[1]
           + hr[4 * kq + 2] * wv[2] + hr[4 * kq + 3] * wv[3];
      }
      s = fmaxf(s, 0.f);
      acc2 += s * fc2w[jf];
    }
    acc2 += __shfl_xor(acc2, 16, 64);
    acc2 += __shfl_xor(acc2, 32, 64);
    if (lane < 16) out[b0 + m] = acc2 + fc2b[0];
  }
}

extern "C" void kernel_launch(void* const* d_in, const int* in_sizes, int n_in,
                              void* d_out, int out_size, void* d_ws, size_t ws_size,
                              hipStream_t stream) {
  const float* x    = (const float*)d_in[0];
  const float* Wih0 = (const float*)d_in[1];
  const float* Whh0 = (const float*)d_in[2];
  const float* bih0 = (const float*)d_in[3];
  const float* bhh0 = (const float*)d_in[4];
  const float* Wih1 = (const float*)d_in[5];
  const float* Whh1 = (const float*)d_in[6];
  const float* bih1 = (const float*)d_in[7];
  const float* bhh1 = (const float*)d_in[8];
  const float* Wih2 = (const float*)d_in[9];
  const float* Whh2 = (const float*)d_in[10];
  const float* bih2 = (const float*)d_in[11];
  const float* bhh2 = (const float*)d_in[12];
  const float* fc1w = (const float*)d_in[13];
  const float* fc1b = (const float*)d_in[14];
  const float* fc2w = (const float*)d_in[15];
  const float* fc2b = (const float*)d_in[16];

  rnn_pipe<<<dim3(4096 / BPB), dim3(192), 0, stream>>>(
      x, Wih0, Whh0, bih0, bhh0, Wih1, Whh1, bih1, bhh1,
      Wih2, Whh2, bih2, bhh2, fc1w, fc1b, fc2w, fc2b, (float*)d_out);
}

// Round 8
// 230.474 us; speedup vs baseline: 1.4298x; 1.0179x over previous
//
#include <hip/hip_runtime.h>

typedef short  s16x8 __attribute__((ext_vector_type(8)));   // 8 bf16 bit patterns
typedef float  f32x4 __attribute__((ext_vector_type(4)));
typedef float  f32x2 __attribute__((ext_vector_type(2)));
typedef unsigned int u32;
typedef unsigned int u32x4 __attribute__((ext_vector_type(4)));
typedef unsigned short u16;

#define DEVI static __device__ __forceinline__

constexpr int T_  = 128;
constexpr int F_  = 14;
constexpr int H_  = 64;
constexpr int BPB = 16;   // batch rows per block

DEVI u16 f2bf(float f) {                     // RNE, one-time weight convert
  u32 u = __builtin_bit_cast(u32, f);
  u += 0x7fffu + ((u >> 16) & 1u);
  return (u16)(u >> 16);
}
DEVI u16 f2bfF(float f) {                    // round-half-up (x / h in-loop path)
  u32 u = __builtin_bit_cast(u32, f);
  return (u16)((u + 0x8000u) >> 16);
}
DEVI u32 pkbf(float a, float b) {            // pack 2 bf16 into one dword
  u32 ua = __builtin_bit_cast(u32, a) + 0x8000u;
  u32 ub = __builtin_bit_cast(u32, b) + 0x8000u;
  return (ua >> 16) | (ub & 0xffff0000u);
}
// B-frag kt from tanh'd acc tiles: elements 0-3 = tile kt, 4-7 = tile kt+2
DEVI s16x8 packfrag(const f32x4& a, const f32x4& b) {
  u32x4 p;
  p[0] = pkbf(a[0], a[1]); p[1] = pkbf(a[2], a[3]);
  p[2] = pkbf(b[0], b[1]); p[3] = pkbf(b[2], b[3]);
  return __builtin_bit_cast(s16x8, p);
}
DEVI float tanhfast(float x) {
  float e = exp2f(x * -2.8853900817779268f);
  float r = __builtin_amdgcn_rcpf(1.0f + e);
  return __builtin_fmaf(2.0f, r, -1.0f);
}
DEVI f32x4 tanh4(const f32x4& v) {
  f32x4 r;
  r[0] = tanhfast(v[0]); r[1] = tanhfast(v[1]);
  r[2] = tanhfast(v[2]); r[3] = tanhfast(v[3]);
  return r;
}
DEVI f32x4 MFMA(s16x8 a, s16x8 b, f32x4 c) {
  return __builtin_amdgcn_mfma_f32_16x16x32_bf16(a, b, c, 0, 0, 0);
}
DEVI s16x8 ldrow8(const float* p) {          // 8 contiguous fp32 -> bf16 A-frag
  const f32x4 a = ((const f32x4*)p)[0];
  const f32x4 b = ((const f32x4*)p)[1];
  s16x8 r;
  r[0] = (short)f2bf(a[0]); r[1] = (short)f2bf(a[1]);
  r[2] = (short)f2bf(a[2]); r[3] = (short)f2bf(a[3]);
  r[4] = (short)f2bf(b[0]); r[5] = (short)f2bf(b[1]);
  r[6] = (short)f2bf(b[2]); r[7] = (short)f2bf(b[3]);
  return r;
}

// 3 waves/block; wave w owns layer w FULLY (round-5-proven structure: weights,
// biases, hh-state all register-resident; row map L(n,rho)=32*(n&1)+8*(rho>>2)
// +4*(n>>1)+(rho&3) makes D->B a pure register repack). Deltas vs round 5:
//  (1) handoff double-buffered -> ONE barrier per epoch (write wb=e&1, read rb).
//  (2) no x LDS staging: wave 0 streams x from global, prefetch distance 3
//      (~2000cy lead >> 900cy HBM) so the barrier's vmcnt drain is free.
//  (3) per-wave MFMA order: register-operand hh-MFMAs first to hide the
//      post-barrier ds_read latency of the prev-layer fragments.
__global__ __launch_bounds__(192, 1) void rnn_p3d(
    const float* __restrict__ x,
    const float* __restrict__ Wih0, const float* __restrict__ Whh0,
    const float* __restrict__ bih0, const float* __restrict__ bhh0,
    const float* __restrict__ Wih1, const float* __restrict__ Whh1,
    const float* __restrict__ bih1, const float* __restrict__ bhh1,
    const float* __restrict__ Wih2, const float* __restrict__ Whh2,
    const float* __restrict__ bih2, const float* __restrict__ bhh2,
    const float* __restrict__ fc1w, const float* __restrict__ fc1b,
    const float* __restrict__ fc2w, const float* __restrict__ fc2b,
    float* __restrict__ out)
{
  __shared__ __align__(16) u32x4 hX[2][2][2][64];   // [buf][layer01][frag][lane] 8 KiB
  __shared__ __align__(16) float h2l[BPB][68];      // fc-head unpermute, 4352 B

  const int tid  = threadIdx.x;
  const int w    = tid >> 6;        // wave id = layer id
  const int lane = tid & 63;
  const int g    = lane >> 4;
  const int m    = lane & 15;
  const int b0   = blockIdx.x * BPB;

  // ---- zero handoff buffers (h(-1)=0; both bufs read before first writes) ----
  {
    u32x4 z; z[0] = 0; z[1] = 0; z[2] = 0; z[3] = 0;
    u32x4* hp = &hX[0][0][0][0];
    #pragma unroll 1
    for (int i = tid; i < 2 * 2 * 2 * 64; i += 192) hp[i] = z;
  }

  // ---- per-wave (per-layer) weights, all register-resident (round-5 exact) ----
  s16x8 Ax[4], Ai[4][2], Ah[4][2];
  f32x4 bc[4];
  {
    const float* Wi = Wih1; const float* Wh = Whh0;
    const float* bi = bih0; const float* bh = bhh0;
    if (w == 1)      { Wi = Wih1; Wh = Whh1; bi = bih1; bh = bhh1; }
    else if (w == 2) { Wi = Wih2; Wh = Whh2; bi = bih2; bh = bhh2; }
    #pragma unroll
    for (int n = 0; n < 4; n++) {
      const int Lr = 32 * (n & 1) + 8 * (m >> 2) + 4 * (n >> 1) + (m & 3);
      if (w == 0) {                      // input side 64x14, zero-pad K to 32
        s16x8 r;
        #pragma unroll
        for (int j2 = 0; j2 < 8; j2++) {
          const int kk = 8 * g + j2;
          r[j2] = (kk < F_) ? (short)f2bf(Wih0[Lr * F_ + kk]) : (short)0;
        }
        Ax[n] = r;
        Ai[n][0] = r; Ai[n][1] = r;      // dead in wave0
      } else {
        #pragma unroll
        for (int kt = 0; kt < 2; kt++)
          Ai[n][kt] = ldrow8(Wi + Lr * H_ + 32 * kt + 8 * g);
        Ax[n] = Ai[n][0];                // dead in waves 1/2
      }
      #pragma unroll
      for (int kt = 0; kt < 2; kt++)
        Ah[n][kt] = ldrow8(Wh + Lr * H_ + 32 * kt + 8 * g);
      const int Lb = 32 * (n & 1) + 8 * g + 4 * (n >> 1);
      bc[n] = *(const f32x4*)(bi + Lb) + *(const f32x4*)(bh + Lb);
    }
  }

  // ---- hh-state frags (own layer), zero init ----
  s16x8 F[2];
  {
    s16x8 z;
    #pragma unroll
    for (int i = 0; i < 8; i++) z[i] = 0;
    F[0] = z; F[1] = z;
  }
  f32x4 h2v[4];
  #pragma unroll
  for (int n = 0; n < 4; n++) { h2v[n][0]=0; h2v[n][1]=0; h2v[n][2]=0; h2v[n][3]=0; }

  // ---- wave-0 x pipeline: global loads, distance-3 prefetch (round-4 proven) ----
  const float* xrow = x + (size_t)(b0 + m) * T_ * F_;
  auto ldraw = [&](int t, f32x4& ra, f32x4& rb) {   // 8B-aligned float2 loads
    const float* p = xrow + t * F_;
    if (g == 0) {
      f32x2 p0 = *(const f32x2*)(p),     p1 = *(const f32x2*)(p + 2);
      f32x2 p2 = *(const f32x2*)(p + 4), p3 = *(const f32x2*)(p + 6);
      ra[0] = p0[0]; ra[1] = p0[1]; ra[2] = p1[0]; ra[3] = p1[1];
      rb[0] = p2[0]; rb[1] = p2[1]; rb[2] = p3[0]; rb[3] = p3[1];
    } else if (g == 1) {
      f32x2 p4 = *(const f32x2*)(p + 8), p5 = *(const f32x2*)(p + 10);
      f32x2 p6 = *(const f32x2*)(p + 12);
      ra[0] = p4[0]; ra[1] = p4[1]; ra[2] = p5[0]; ra[3] = p5[1];
      rb[0] = p6[0]; rb[1] = p6[1]; rb[2] = 0.f;   rb[3] = 0.f;
    } else {
      ra[0]=0.f; ra[1]=0.f; ra[2]=0.f; ra[3]=0.f;
      rb[0]=0.f; rb[1]=0.f; rb[2]=0.f; rb[3]=0.f;
    }
  };
  auto cvtraw = [&](const f32x4& ra, const f32x4& rb) -> s16x8 {
    s16x8 r;
    r[0] = (short)f2bfF(ra[0]); r[1] = (short)f2bfF(ra[1]);
    r[2] = (short)f2bfF(ra[2]); r[3] = (short)f2bfF(ra[3]);
    r[4] = (short)f2bfF(rb[0]); r[5] = (short)f2bfF(rb[1]);
    r[6] = (short)f2bfF(rb[2]); r[7] = (short)f2bfF(rb[3]);
    return r;
  };
  s16x8 bx;
  f32x4 Ba0, Ba1, Ca0, Ca1, Da0, Da1;
  if (w == 0) {
    f32x4 t0, t1;
    ldraw(0, t0, t1); bx = cvtraw(t0, t1);   // frag for t=0
    ldraw(1, Ba0, Ba1);                       // raw x[1]
    ldraw(2, Ca0, Ca1);                       // raw x[2]
  }

  __syncthreads();   // hX zeros visible

  // ---- pipelined T-loop: ONE barrier per epoch (double-buffered handoff) ----
  #pragma unroll 1
  for (int e = 0; e < T_ + 2; e++) {
    const int t  = e - w;
    const int wb = e & 1, rb = wb ^ 1;

    if (w == 0) {                        // keep distance-3 prefetch in flight
      int tp = e + 3; if (tp > T_ - 1) tp = T_ - 1;
      ldraw(tp, Da0, Da1);
    }

    // R: read prev-layer frags from the buffer written LAST epoch
    s16x8 Fp0, Fp1;
    if (w == 1) {
      Fp0 = __builtin_bit_cast(s16x8, hX[rb][0][0][lane]);
      Fp1 = __builtin_bit_cast(s16x8, hX[rb][0][1][lane]);
    } else if (w == 2) {
      Fp0 = __builtin_bit_cast(s16x8, hX[rb][1][0][lane]);
      Fp1 = __builtin_bit_cast(s16x8, hX[rb][1][1][lane]);
    } else {
      Fp0 = bx; Fp1 = bx;                // wave0: input already in registers
    }

    if (t >= 0 && t < T_) {              // wave-uniform
      f32x4 a[4];
      // hh-MFMAs first: register operands, hide the ds_read latency of Fp
      #pragma unroll
      for (int n = 0; n < 4; n++) {
        f32x4 v = bc[n];
        v = MFMA(Ah[n][0], F[0], v);
        v = MFMA(Ah[n][1], F[1], v);
        a[n] = v;
      }
      #pragma unroll
      for (int n = 0; n < 4; n++) {
        if (w == 0) {
          a[n] = MFMA(Ax[n], Fp0, a[n]);
        } else {
          a[n] = MFMA(Ai[n][0], Fp0, a[n]);
          a[n] = MFMA(Ai[n][1], Fp1, a[n]);
        }
      }
      f32x4 hv[4];
      #pragma unroll
      for (int n = 0; n < 4; n++) hv[n] = tanh4(a[n]);
      F[0] = packfrag(hv[0], hv[2]);
      F[1] = packfrag(hv[1], hv[3]);
      if (w == 0) {
        hX[wb][0][0][lane] = __builtin_bit_cast(u32x4, F[0]);
        hX[wb][0][1][lane] = __builtin_bit_cast(u32x4, F[1]);
      } else if (w == 1) {
        hX[wb][1][0][lane] = __builtin_bit_cast(u32x4, F[0]);
        hX[wb][1][1][lane] = __builtin_bit_cast(u32x4, F[1]);
      } else if (t == T_ - 1) {
        #pragma unroll
        for (int n = 0; n < 4; n++) h2v[n] = hv[n];   // fp32 h2 for head
      }
    }

    if (w == 0) {                        // rotate x pipeline (after bx consumed)
      bx = cvtraw(Ba0, Ba1);
      Ba0 = Ca0; Ba1 = Ca1; Ca0 = Da0; Ca1 = Da1;
    }
    __syncthreads();   // single END barrier: wb visible next epoch; rb reads drained
  }

  // ---- FC head: wave 2 un-permutes fp32 h2; wave 0 computes (round-5 exact) ----
  if (w == 2) {
    #pragma unroll
    for (int n = 0; n < 4; n++) {
      const int Lb = 32 * (n & 1) + 8 * g + 4 * (n >> 1);
      *(f32x4*)&h2l[m][Lb] = h2v[n];
    }
  }
  __syncthreads();

  if (w == 0) {
    float hr[64];
    #pragma unroll
    for (int q = 0; q < 16; q++) {
      f32x4 v = *(const f32x4*)&h2l[m][4 * q];
      hr[4 * q + 0] = v[0]; hr[4 * q + 1] = v[1];
      hr[4 * q + 2] = v[2]; hr[4 * q + 3] = v[3];
    }
    float acc2 = 0.f;
    #pragma unroll
    for (int jj = 0; jj < 8; jj++) {
      const int jf = 8 * g + jj;
      float s = fc1b[jf];
      const f32x4* wp = (const f32x4*)(fc1w + jf * H_);
      #pragma unroll
      for (int kq = 0; kq < 16; kq++) {
        f32x4 wv = wp[kq];
        s += hr[4 * kq + 0] * wv[0] + hr[4 * kq + 1] * wv[1]
           + hr[4 * kq + 2] * wv[2] + hr[4 * kq + 3] * wv[3];
      }
      s = fmaxf(s, 0.f);
      acc2 += s * fc2w[jf];
    }
    acc2 += __shfl_xor(acc2, 16, 64);
    acc2 += __shfl_xor(acc2, 32, 64);
    if (lane < 16) out[b0 + m] = acc2 + fc2b[0];
  }
}

extern "C" void kernel_launch(void* const* d_in, const int* in_sizes, int n_in,
                              void* d_out, int out_size, void* d_ws, size_t ws_size,
                              hipStream_t stream) {
  const float* x    = (const float*)d_in[0];
  const float* Wih0 = (const float*)d_in[1];
  const float* Whh0 = (const float*)d_in[2];
  const float* bih0 = (const float*)d_in[3];
  const float* bhh0 = (const float*)d_in[4];
  const float* Wih1 = (const float*)d_in[5];
  const float* Whh1 = (const float*)d_in[6];
  const float* bih1 = (const float*)d_in[7];
  const float* bhh1 = (const float*)d_in[8];
  const float* Wih2 = (const float*)d_in[9];
  const float* Whh2 = (const float*)d_in[10];
  const float* bih2 = (const float*)d_in[11];
  const float* bhh2 = (const float*)d_in[12];
  const float* fc1w = (const float*)d_in[13];
  const float* fc1b = (const float*)d_in[14];
  const float* fc2w = (const float*)d_in[15];
  const float* fc2b = (const float*)d_in[16];

  rnn_p3d<<<dim3(4096 / BPB), dim3(192), 0, stream>>>(
      x, Wih0, Whh0, bih0, bhh0, Wih1, Whh1, bih1, bhh1,
      Wih2, Whh2, bih2, bhh2, fc1w, fc1b, fc2w, fc2b, (float*)d_out);
}